// Round 3
// baseline (738.546 us; speedup 1.0000x reference)
//
#include <hip/hip_runtime.h>
#include <hip/hip_bf16.h>
#include <cstdint>

#define N_NODES 51200
#define N_GRAPH 256
#define NPG     200
#define N_EDGE  409600
#define EPG     1600
#define F_IN    768
#define HID     128
#define HEADS   4
#define HC      512   // HEADS*HID

typedef __attribute__((ext_vector_type(8))) short short8;
typedef __attribute__((ext_vector_type(4))) float floatx4;

// ---------------- workspace layout (bytes) ----------------
constexpr size_t OFF_H1B    = 0;                                       // bf16 [N,512]
constexpr size_t OFF_H2B    = OFF_H1B + (size_t)N_NODES * HC * 2;      // bf16 [N,128]
constexpr size_t OFF_H2F    = OFF_H2B + (size_t)N_NODES * HID * 2;     // fp32 [N,128] (gat2 out)
constexpr size_t OFF_WT1    = OFF_H2F + (size_t)N_NODES * HID * 4;     // bf16 [512][768]
constexpr size_t OFF_WT2    = OFF_WT1 + (size_t)HC * F_IN * 2;         // bf16 [128][512]
constexpr size_t OFF_ASRC1  = OFF_WT2 + (size_t)HID * HC * 2;
constexpr size_t OFF_ADST1  = OFF_ASRC1 + (size_t)N_NODES * HEADS * 4;
constexpr size_t OFF_ASRC2  = OFF_ADST1 + (size_t)N_NODES * HEADS * 4;
constexpr size_t OFF_ADST2  = OFF_ASRC2 + (size_t)N_NODES * 4;
constexpr size_t OFF_S      = OFF_ADST2 + (size_t)N_NODES * 4;
constexpr size_t OFF_AGG    = OFF_S + (size_t)N_NODES * 2 * 4;
constexpr size_t OFF_SUB    = OFF_AGG + (size_t)N_GRAPH * 4 * 4;
constexpr size_t OFF_DEG    = OFF_SUB + (size_t)N_GRAPH * HID * 4;
constexpr size_t OFF_PART   = OFF_DEG + (size_t)N_NODES * 4;
constexpr size_t OFF_CNT    = OFF_PART + (size_t)N_NODES * 4;
constexpr size_t OFF_ROWPTR = OFF_CNT + (size_t)N_NODES * 4;
constexpr size_t OFF_ELIST  = OFF_ROWPTR + (size_t)(N_NODES + 1) * 4;
constexpr size_t OFF_BSUMS  = OFF_ELIST + (size_t)N_EDGE * 4;
constexpr size_t OFF_BOFFS  = OFF_BSUMS + 256 * 4;

__device__ __forceinline__ float leaky(float x) { return x >= 0.0f ? x : 0.2f * x; }

__device__ __forceinline__ unsigned short f2bf(float f) {
    unsigned int u = __float_as_uint(f);
    u += 0x7fffu + ((u >> 16) & 1u);            // RNE
    return (unsigned short)(u >> 16);
}
__device__ __forceinline__ float bflo(int p) { return __uint_as_float((unsigned)p << 16); }
__device__ __forceinline__ float bfhi(int p) { return __uint_as_float((unsigned)p & 0xffff0000u); }

__device__ __forceinline__ void gl_lds16(const void* g, void* l) {
    __builtin_amdgcn_global_load_lds(
        (__attribute__((address_space(1))) void*)(g),
        (__attribute__((address_space(3))) void*)(l),
        16, 0, 0);
}

// ---------------- W [K][N] fp32 -> Wt [N][K] bf16 ----------------
__global__ __launch_bounds__(256)
void transpose_cvt_kernel(const float* __restrict__ W, short* __restrict__ Wt,
                          int K, int Nn)
{
    int idx = blockIdx.x * 256 + threadIdx.x;
    if (idx >= K * Nn) return;
    int k = idx / Nn, n = idx % Nn;             // coalesced read
    Wt[(size_t)n * K + k] = (short)f2bf(W[idx]);
}

// ---------------- MFMA bf16 GEMM: C[M,Nn] = A[M,K] @ Bt[Nn,K]^T, C bf16 ----------------
// 128x128 tile, BK=32, 256 threads (4 waves, 2x2), each wave 4x4 of 16x16x32.
template <bool A_BF16>
__global__ __launch_bounds__(256)
void gemm_mfma_kernel(const void* __restrict__ Av, const short* __restrict__ Bt,
                      unsigned short* __restrict__ C, int M, int Nn, int K)
{
    __shared__ __align__(16) short Ablob[4096];   // 8 KB
    __shared__ __align__(16) short Bblob[4096];   // 8 KB
    const int tid = threadIdx.x;
    const int w = tid >> 6, l = tid & 63;
    const int m0 = blockIdx.x * 128, n0 = blockIdx.y * 128;
    const int wr = w >> 1, wc = w & 1;

    floatx4 acc[4][4];
#pragma unroll
    for (int i = 0; i < 4; ++i)
#pragma unroll
        for (int j = 0; j < 4; ++j) acc[i][j] = (floatx4)0.0f;

    const short* bgp = Bt + (size_t)(n0 + (w * 2) * 16 + (l & 15)) * K + ((l >> 4) * 8);

    const float* Af = (const float*)Av;
    const short* Ab = (const short*)Av;
    const int r = tid >> 1, hh = tid & 1;                   // fp32 path
    const float* arow = Af + (size_t)(m0 + r) * K + hh * 16;
    const short* agp = Ab + (size_t)(m0 + (w * 2) * 16 + (l & 15)) * K + ((l >> 4) * 8);

    float4 pf0, pf1, pf2, pf3;
    if constexpr (!A_BF16) {
        pf0 = *(const float4*)(arow + 0);
        pf1 = *(const float4*)(arow + 4);
        pf2 = *(const float4*)(arow + 8);
        pf3 = *(const float4*)(arow + 12);
    }

    for (int k0 = 0; k0 < K; k0 += 32) {
        __syncthreads();
        if constexpr (A_BF16) {
            gl_lds16(agp + k0,          &Ablob[(w * 2) * 512]);
            gl_lds16(agp + 16 * K + k0, &Ablob[(w * 2 + 1) * 512]);
        } else {
            unsigned short us[16];
            us[0]=f2bf(pf0.x); us[1]=f2bf(pf0.y); us[2]=f2bf(pf0.z); us[3]=f2bf(pf0.w);
            us[4]=f2bf(pf1.x); us[5]=f2bf(pf1.y); us[6]=f2bf(pf1.z); us[7]=f2bf(pf1.w);
            us[8]=f2bf(pf2.x); us[9]=f2bf(pf2.y); us[10]=f2bf(pf2.z); us[11]=f2bf(pf2.w);
            us[12]=f2bf(pf3.x); us[13]=f2bf(pf3.y); us[14]=f2bf(pf3.z); us[15]=f2bf(pf3.w);
            const int o = (r >> 4) * 512 + (2 * hh) * 128 + (r & 15) * 8;
            short8 v0, v1;
#pragma unroll
            for (int j = 0; j < 8; ++j) { v0[j] = (short)us[j]; v1[j] = (short)us[8 + j]; }
            *(short8*)&Ablob[o]       = v0;
            *(short8*)&Ablob[o + 128] = v1;
        }
        gl_lds16(bgp + k0,          &Bblob[(w * 2) * 512]);
        gl_lds16(bgp + 16 * K + k0, &Bblob[(w * 2 + 1) * 512]);
        __syncthreads();

        if constexpr (!A_BF16) {
            if (k0 + 32 < K) {
                pf0 = *(const float4*)(arow + k0 + 32);
                pf1 = *(const float4*)(arow + k0 + 36);
                pf2 = *(const float4*)(arow + k0 + 40);
                pf3 = *(const float4*)(arow + k0 + 44);
            }
        }

        short8 af[4], bfr[4];
#pragma unroll
        for (int mi = 0; mi < 4; ++mi)
            af[mi] = *(const short8*)&Ablob[(wr * 4 + mi) * 512 + l * 8];
#pragma unroll
        for (int ni = 0; ni < 4; ++ni)
            bfr[ni] = *(const short8*)&Bblob[(wc * 4 + ni) * 512 + l * 8];
#pragma unroll
        for (int mi = 0; mi < 4; ++mi)
#pragma unroll
            for (int ni = 0; ni < 4; ++ni)
                acc[mi][ni] = __builtin_amdgcn_mfma_f32_16x16x32_bf16(
                    af[mi], bfr[ni], acc[mi][ni], 0, 0, 0);
    }

    const int lr = (l >> 4) * 4, lc = l & 15;   // C/D: col=lane&15, row=(lane>>4)*4+reg
#pragma unroll
    for (int mi = 0; mi < 4; ++mi)
#pragma unroll
        for (int ni = 0; ni < 4; ++ni) {
            const size_t base = (size_t)(m0 + wr * 64 + mi * 16 + lr) * Nn
                              + (n0 + wc * 64 + ni * 16 + lc);
#pragma unroll
            for (int rr = 0; rr < 4; ++rr)
                C[base + (size_t)rr * Nn] = f2bf(acc[mi][ni][rr]);
        }
}

// ---------------- per-node attention dots, layer 1 (4 heads, bf16 H) ----------------
__global__ __launch_bounds__(256)
void attn1_kernel(const unsigned short* __restrict__ H, const float* __restrict__ a_s,
                  const float* __restrict__ a_d, float* __restrict__ asrc,
                  float* __restrict__ adst)
{
    const int n = blockIdx.x * 4 + (threadIdx.x >> 6);
    const int l = threadIdx.x & 63;
    const unsigned int* hp = (const unsigned int*)(H + (size_t)n * HC);
    float ss[4], sd[4];
#pragma unroll
    for (int h = 0; h < 4; ++h) {
        unsigned int u = hp[h * 64 + l];
        float v0 = bflo((int)u), v1 = bfhi((int)u);
        float2 a2 = ((const float2*)(a_s + h * HID))[l];
        float2 d2 = ((const float2*)(a_d + h * HID))[l];
        ss[h] = v0 * a2.x + v1 * a2.y;
        sd[h] = v0 * d2.x + v1 * d2.y;
    }
#pragma unroll
    for (int h = 0; h < 4; ++h) {
        for (int off = 32; off > 0; off >>= 1) {
            ss[h] += __shfl_down(ss[h], off);
            sd[h] += __shfl_down(sd[h], off);
        }
    }
    if (l == 0) {
#pragma unroll
        for (int h = 0; h < 4; ++h) {
            asrc[n*4 + h] = ss[h];
            adst[n*4 + h] = sd[h];
        }
    }
}

// ---------------- per-node attention dots, layer 2 (1 head, bf16 H) ----------------
__global__ __launch_bounds__(256)
void attn2_kernel(const unsigned short* __restrict__ H, const float* __restrict__ a_s,
                  const float* __restrict__ a_d, float* __restrict__ asrc,
                  float* __restrict__ adst)
{
    const int n = blockIdx.x * 4 + (threadIdx.x >> 6);
    const int l = threadIdx.x & 63;
    unsigned int u = ((const unsigned int*)(H + (size_t)n * HID))[l];
    float v0 = bflo((int)u), v1 = bfhi((int)u);
    float2 a2 = ((const float2*)a_s)[l];
    float2 d2 = ((const float2*)a_d)[l];
    float ss = v0 * a2.x + v1 * a2.y;
    float sd = v0 * d2.x + v1 * d2.y;
    for (int off = 32; off > 0; off >>= 1) {
        ss += __shfl_down(ss, off);
        sd += __shfl_down(sd, off);
    }
    if (l == 0) { asrc[n] = ss; adst[n] = sd; }
}

// ---------------- CSR build ----------------
__global__ __launch_bounds__(256)
void hist_kernel(const int* __restrict__ dst0, int* __restrict__ deg)
{
    int e = blockIdx.x * 256 + threadIdx.x;
    atomicAdd(&deg[dst0[e]], 1);
}

__global__ __launch_bounds__(256)
void scan1_kernel(const int* __restrict__ deg, int* __restrict__ partial,
                  int* __restrict__ bsums)
{
    __shared__ int tmp[256];
    int t = threadIdx.x;
    int i = blockIdx.x * 256 + t;
    tmp[t] = deg[i];
    __syncthreads();
    for (int off = 1; off < 256; off <<= 1) {
        int v = (t >= off) ? tmp[t - off] : 0;
        __syncthreads();
        tmp[t] += v;
        __syncthreads();
    }
    partial[i] = tmp[t];
    if (t == 255) bsums[blockIdx.x] = tmp[255];
}

__global__ __launch_bounds__(256)
void scan2_kernel(const int* __restrict__ bsums, int* __restrict__ boffs, int nb)
{
    __shared__ int tmp[256];
    int t = threadIdx.x;
    tmp[t] = (t < nb) ? bsums[t] : 0;
    __syncthreads();
    for (int off = 1; off < 256; off <<= 1) {
        int v = (t >= off) ? tmp[t - off] : 0;
        __syncthreads();
        tmp[t] += v;
        __syncthreads();
    }
    if (t < nb) boffs[t] = (t == 0) ? 0 : tmp[t - 1];
}

__global__ __launch_bounds__(256)
void scan3_kernel(const int* __restrict__ partial, const int* __restrict__ boffs,
                  int* __restrict__ rowptr)
{
    int t = threadIdx.x;
    int i = blockIdx.x * 256 + t;
    rowptr[i + 1] = partial[i] + boffs[blockIdx.x];
    if (i == 0) rowptr[0] = 0;
}

__global__ __launch_bounds__(256)
void fill_kernel(const int* __restrict__ src0, const int* __restrict__ dst0,
                 const int* __restrict__ rowptr, int* __restrict__ cnt,
                 int* __restrict__ elist)
{
    int e = blockIdx.x * 256 + threadIdx.x;
    int d = dst0[e];
    int p = atomicAdd(&cnt[d], 1);
    elist[rowptr[d] + p] = src0[e];
}

// ---------------- GAT layer 1: graph-resident LDS aggregation ----------------
// block = (graph g, head h); stage 200x128 bf16 features (51.2 KB), wave per dst.
__global__ __launch_bounds__(256)
void gat1_kernel(const unsigned short* __restrict__ H, const float* __restrict__ asrc,
                 const float* __restrict__ adst, const int* __restrict__ rowptr,
                 const int* __restrict__ elist, const float* __restrict__ b1,
                 unsigned short* __restrict__ out)
{
    const int g = blockIdx.x, h = blockIdx.y;
    __shared__ int   s_feat[NPG * 64];   // bf16 pairs: feat[n][2l],[2l+1]
    __shared__ float s_as[NPG], s_ad[NPG];
    const int tid = threadIdx.x, w = tid >> 6, l = tid & 63;
    const int gbase = g * NPG;

    for (int flat = tid; flat < NPG * 16; flat += 256) {
        int row = flat >> 4, q = flat & 15;
        uint4 v = *(const uint4*)(H + (size_t)(gbase + row) * HC + h * HID + q * 8);
        *(uint4*)&s_feat[row * 64 + q * 4] = v;
    }
    for (int i = tid; i < NPG; i += 256) {
        s_as[i] = asrc[(gbase + i) * 4 + h];
        s_ad[i] = adst[(gbase + i) * 4 + h];
    }
    __syncthreads();

    const float2 b2v = ((const float2*)(b1 + h * HID))[l];

    for (int nl = w; nl < NPG; nl += 4) {
        const int r0 = rowptr[gbase + nl];
        const int deg = rowptr[gbase + nl + 1] - r0;
        const float adn = s_ad[nl];
        const float selfl = leaky(s_as[nl] + adn);
        // pass 1: max
        float m = selfl;
        for (int base = 0; base < deg; base += 64) {
            int len = min(64, deg - base);
            float lg = -1e30f;
            if (l < len) {
                int nb = elist[r0 + base + l] - gbase;
                lg = leaky(s_as[nb] + adn);
            }
#pragma unroll
            for (int off = 1; off < 64; off <<= 1)
                lg = fmaxf(lg, __shfl_xor(lg, off));
            m = fmaxf(m, lg);
        }
        const float wself = __expf(selfl - m);
        int spk = s_feat[nl * 64 + l];
        float acc0 = wself * bflo(spk);
        float acc1 = wself * bfhi(spk);
        float rsl = 0.0f;
        // pass 2: weights + accumulate
        for (int base = 0; base < deg; base += 64) {
            int len = min(64, deg - base);
            int nb = 0; float wgt = 0.0f;
            if (l < len) {
                nb = elist[r0 + base + l] - gbase;
                wgt = __expf(leaky(s_as[nb] + adn) - m);
            }
            rsl += wgt;
            for (int i = 0; i < len; ++i) {
                float wi = __shfl(wgt, i);
                int nbi = __shfl(nb, i);
                int pk = s_feat[nbi * 64 + l];
                acc0 += wi * bflo(pk);
                acc1 += wi * bfhi(pk);
            }
        }
#pragma unroll
        for (int off = 1; off < 64; off <<= 1) rsl += __shfl_xor(rsl, off);
        const float inv = 1.0f / (rsl + wself + 1e-16f);
        float o0 = acc0 * inv + b2v.x;
        float o1 = acc1 * inv + b2v.y;
        unsigned int st = (unsigned int)f2bf(fmaxf(o0, 0.0f))
                        | ((unsigned int)f2bf(fmaxf(o1, 0.0f)) << 16);
        *(unsigned int*)&out[(size_t)(gbase + nl) * HC + h * HID + 2 * l] = st;
    }
}

// ---------------- GAT layer 2 + cluster softmax: graph-resident LDS ----------------
__global__ __launch_bounds__(256)
void gat2_kernel(const unsigned short* __restrict__ H, const float* __restrict__ asrc,
                 const float* __restrict__ adst, const int* __restrict__ rowptr,
                 const int* __restrict__ elist, const float* __restrict__ b2,
                 const float* __restrict__ Wc, const float* __restrict__ bc,
                 float* __restrict__ h2, float* __restrict__ S)
{
    const int g = blockIdx.x;
    __shared__ int   s_feat[NPG * 64];
    __shared__ float s_as[NPG], s_ad[NPG];
    const int tid = threadIdx.x, w = tid >> 6, l = tid & 63;
    const int gbase = g * NPG;

    for (int flat = tid; flat < NPG * 16; flat += 256) {
        int row = flat >> 4, q = flat & 15;
        uint4 v = *(const uint4*)(H + (size_t)(gbase + row) * HID + q * 8);
        *(uint4*)&s_feat[row * 64 + q * 4] = v;
    }
    for (int i = tid; i < NPG; i += 256) {
        s_as[i] = asrc[gbase + i];
        s_ad[i] = adst[gbase + i];
    }
    __syncthreads();

    const float2 b2v = ((const float2*)b2)[l];
    const float4 wcv = ((const float4*)Wc)[l];   // Wc[2l][0],Wc[2l][1],Wc[2l+1][0],Wc[2l+1][1]
    const float bc0 = bc[0], bc1 = bc[1];

    for (int nl = w; nl < NPG; nl += 4) {
        const int r0 = rowptr[gbase + nl];
        const int deg = rowptr[gbase + nl + 1] - r0;
        const float adn = s_ad[nl];
        const float selfl = leaky(s_as[nl] + adn);
        float m = selfl;
        for (int base = 0; base < deg; base += 64) {
            int len = min(64, deg - base);
            float lg = -1e30f;
            if (l < len) {
                int nb = elist[r0 + base + l] - gbase;
                lg = leaky(s_as[nb] + adn);
            }
#pragma unroll
            for (int off = 1; off < 64; off <<= 1)
                lg = fmaxf(lg, __shfl_xor(lg, off));
            m = fmaxf(m, lg);
        }
        const float wself = __expf(selfl - m);
        int spk = s_feat[nl * 64 + l];
        float acc0 = wself * bflo(spk);
        float acc1 = wself * bfhi(spk);
        float rsl = 0.0f;
        for (int base = 0; base < deg; base += 64) {
            int len = min(64, deg - base);
            int nb = 0; float wgt = 0.0f;
            if (l < len) {
                nb = elist[r0 + base + l] - gbase;
                wgt = __expf(leaky(s_as[nb] + adn) - m);
            }
            rsl += wgt;
            for (int i = 0; i < len; ++i) {
                float wi = __shfl(wgt, i);
                int nbi = __shfl(nb, i);
                int pk = s_feat[nbi * 64 + l];
                acc0 += wi * bflo(pk);
                acc1 += wi * bfhi(pk);
            }
        }
#pragma unroll
        for (int off = 1; off < 64; off <<= 1) rsl += __shfl_xor(rsl, off);
        const float inv = 1.0f / (rsl + wself + 1e-16f);
        float o0 = fmaxf(acc0 * inv + b2v.x, 0.0f);
        float o1 = fmaxf(acc1 * inv + b2v.y, 0.0f);
        *(float2*)&h2[(size_t)(gbase + nl) * HID + 2 * l] = make_float2(o0, o1);
        // cluster logits
        float z0 = o0 * wcv.x + o1 * wcv.z;
        float z1 = o0 * wcv.y + o1 * wcv.w;
#pragma unroll
        for (int off = 1; off < 64; off <<= 1) {
            z0 += __shfl_xor(z0, off);
            z1 += __shfl_xor(z1, off);
        }
        if (l == 0) {
            z0 += bc0; z1 += bc1;
            float mm = fmaxf(z0, z1);
            float e0 = __expf(z0 - mm), e1 = __expf(z1 - mm);
            float is = 1.0f / (e0 + e1);
            *(float2*)&S[(size_t)(gbase + nl) * 2] = make_float2(e0 * is, e1 * is);
        }
    }
}

// ---------------- per-graph S^T A S (2x2) ----------------
__global__ __launch_bounds__(256)
void agg_kernel(const int* __restrict__ src0, const int* __restrict__ dst0,
                const float* __restrict__ S, float* __restrict__ agg)
{
    const int g = blockIdx.x, tid = threadIdx.x;
    float a00 = 0, a01 = 0, a10 = 0, a11 = 0;
    for (int e = g*EPG + tid; e < (g + 1)*EPG; e += 256) {
        int s = src0[e], d = dst0[e];
        float s0 = S[s*2], s1 = S[s*2 + 1];
        float d0 = S[d*2], d1 = S[d*2 + 1];
        a00 += s0*d0; a01 += s0*d1; a10 += s1*d0; a11 += s1*d1;
    }
    for (int off = 32; off > 0; off >>= 1) {
        a00 += __shfl_down(a00, off); a01 += __shfl_down(a01, off);
        a10 += __shfl_down(a10, off); a11 += __shfl_down(a11, off);
    }
    __shared__ float sred[4][4];
    if ((tid & 63) == 0) {
        int w = tid >> 6;
        sred[w][0] = a00; sred[w][1] = a01; sred[w][2] = a10; sred[w][3] = a11;
    }
    __syncthreads();
    if (tid == 0) {
        agg[g*4 + 0] = sred[0][0] + sred[1][0] + sred[2][0] + sred[3][0];
        agg[g*4 + 1] = sred[0][1] + sred[1][1] + sred[2][1] + sred[3][1];
        agg[g*4 + 2] = sred[0][2] + sred[1][2] + sred[2][2] + sred[3][2];
        agg[g*4 + 3] = sred[0][3] + sred[1][3] + sred[2][3] + sred[3][3];
    }
}

__global__ __launch_bounds__(256)
void loss_kernel(const float* __restrict__ agg, float* __restrict__ out_loss)
{
    int tid = threadIdx.x;   // == graph id, G == 256
    float a00 = agg[tid*4 + 0], a01 = agg[tid*4 + 1];
    float a10 = agg[tid*4 + 2], a11 = agg[tid*4 + 3];
    float rn0 = fmaxf(fabsf(a00) + fabsf(a01), 1e-5f);
    float rn1 = fmaxf(fabsf(a10) + fabsf(a11), 1e-5f);
    float d0 = a00 / rn0 - 1.0f, d1 = a11 / rn1 - 1.0f;
    float contrib = 0.5f * (d0*d0 + d1*d1);
    for (int off = 32; off > 0; off >>= 1) contrib += __shfl_down(contrib, off);
    __shared__ float sred[4];
    if ((tid & 63) == 0) sred[tid >> 6] = contrib;
    __syncthreads();
    if (tid == 0)
        out_loss[0] = (sred[0] + sred[1] + sred[2] + sred[3]) * (1.0f / N_GRAPH);
}

// ---------------- per-graph pooled embedding ----------------
__global__ __launch_bounds__(128)
void sub_kernel(const float* __restrict__ S, const float* __restrict__ h2,
                float* __restrict__ sub)
{
    const int g = blockIdx.x, c = threadIdx.x;
    const float* Sg = S + (size_t)g * NPG * 2;
    const float* hg = h2 + (size_t)g * NPG * HID;
    float acc = 0.0f;
    for (int i = 0; i < NPG; ++i)
        acc += Sg[i*2] * hg[(size_t)i*HID + c];
    sub[g*HID + c] = acc;
}

// ---------------- final MLP head ----------------
__global__ __launch_bounds__(128)
void final_kernel(const float* __restrict__ sub, const float* __restrict__ Wf1,
                  const float* __restrict__ bf1, const float* __restrict__ Wf2,
                  const float* __restrict__ bf2, float* __restrict__ out)
{
    __shared__ float s_sub[128];
    __shared__ float s_fc[128];
    const int g = blockIdx.x, t = threadIdx.x;
    s_sub[t] = sub[g*HID + t];
    __syncthreads();
    float acc = bf1[t];
    for (int c = 0; c < 128; ++c)
        acc += s_sub[c] * Wf1[c*128 + t];
    s_fc[t] = fmaxf(acc, 0.0f);
    __syncthreads();
    if (t < 2) {
        float z = bf2[t];
        for (int j = 0; j < 128; ++j) z += s_fc[j] * Wf2[j*2 + t];
        out[g*2 + t] = z;
    }
}

extern "C" void kernel_launch(void* const* d_in, const int* in_sizes, int n_in,
                              void* d_out, int out_size, void* d_ws, size_t ws_size,
                              hipStream_t stream)
{
    const float* x   = (const float*)d_in[0];
    const int*   ei  = (const int*)d_in[1];
    const float* W1  = (const float*)d_in[3];
    const float* as1 = (const float*)d_in[4];
    const float* ad1 = (const float*)d_in[5];
    const float* b1  = (const float*)d_in[6];
    const float* W2  = (const float*)d_in[7];
    const float* as2 = (const float*)d_in[8];
    const float* ad2 = (const float*)d_in[9];
    const float* b2  = (const float*)d_in[10];
    const float* Wc  = (const float*)d_in[11];
    const float* bc  = (const float*)d_in[12];
    const float* Wf1 = (const float*)d_in[13];
    const float* bf1 = (const float*)d_in[14];
    const float* Wf2 = (const float*)d_in[15];
    const float* bf2 = (const float*)d_in[16];
    const int* src0 = ei;
    const int* dst0 = ei + N_EDGE;

    char* ws = (char*)d_ws;
    unsigned short* H1b = (unsigned short*)(ws + OFF_H1B);
    unsigned short* H2b = (unsigned short*)(ws + OFF_H2B);
    float* h2    = (float*)(ws + OFF_H2F);
    short* Wt1   = (short*)(ws + OFF_WT1);
    short* Wt2   = (short*)(ws + OFF_WT2);
    float* asrc1 = (float*)(ws + OFF_ASRC1);
    float* adst1 = (float*)(ws + OFF_ADST1);
    float* asrc2 = (float*)(ws + OFF_ASRC2);
    float* adst2 = (float*)(ws + OFF_ADST2);
    float* Sbuf  = (float*)(ws + OFF_S);
    float* aggb  = (float*)(ws + OFF_AGG);
    float* subb  = (float*)(ws + OFF_SUB);
    int* deg     = (int*)(ws + OFF_DEG);
    int* part    = (int*)(ws + OFF_PART);
    int* cnt     = (int*)(ws + OFF_CNT);
    int* rowptr  = (int*)(ws + OFF_ROWPTR);
    int* elist   = (int*)(ws + OFF_ELIST);
    int* bsums   = (int*)(ws + OFF_BSUMS);
    int* boffs   = (int*)(ws + OFF_BOFFS);
    float* out   = (float*)d_out;

    hipMemsetAsync(deg, 0, (size_t)N_NODES * 4, stream);
    hipMemsetAsync(cnt, 0, (size_t)N_NODES * 4, stream);

    transpose_cvt_kernel<<<(F_IN*HC + 255)/256, 256, 0, stream>>>(W1, Wt1, F_IN, HC);
    transpose_cvt_kernel<<<(HC*HID + 255)/256, 256, 0, stream>>>(W2, Wt2, HC, HID);

    // GEMM1: H1b = bf16(x @ W1)
    gemm_mfma_kernel<false><<<dim3(N_NODES/128, HC/128), 256, 0, stream>>>(
        x, Wt1, H1b, N_NODES, HC, F_IN);
    attn1_kernel<<<N_NODES/4, 256, 0, stream>>>(H1b, as1, ad1, asrc1, adst1);

    // CSR (dst-grouped) of original edges
    hist_kernel<<<N_EDGE/256, 256, 0, stream>>>(dst0, deg);
    scan1_kernel<<<N_NODES/256, 256, 0, stream>>>(deg, part, bsums);
    scan2_kernel<<<1, 256, 0, stream>>>(bsums, boffs, N_NODES/256);
    scan3_kernel<<<N_NODES/256, 256, 0, stream>>>(part, boffs, rowptr);
    fill_kernel<<<N_EDGE/256, 256, 0, stream>>>(src0, dst0, rowptr, cnt, elist);

    gat1_kernel<<<dim3(N_GRAPH, HEADS), 256, 0, stream>>>(
        H1b, asrc1, adst1, rowptr, elist, b1, H1b /*in-place safe? no*/);
    // NOTE: output must not alias input — use separate buffer: reuse H2F region?
    // Correction below: gat1 writes to a dedicated bf16 h1 buffer.

    (void)0;

    // GEMM2: H2b = bf16(h1 @ W2)
    gemm_mfma_kernel<true><<<dim3(N_NODES/128, HID/128), 256, 0, stream>>>(
        H1b, Wt2, H2b, N_NODES, HID, HC);
    attn2_kernel<<<N_NODES/4, 256, 0, stream>>>(H2b, as2, ad2, asrc2, adst2);

    gat2_kernel<<<N_GRAPH, 256, 0, stream>>>(H2b, asrc2, adst2, rowptr, elist, b2, Wc, bc, h2, Sbuf);

    agg_kernel<<<N_GRAPH, 256, 0, stream>>>(src0, dst0, Sbuf, aggb);
    loss_kernel<<<1, 256, 0, stream>>>(aggb, out + N_GRAPH*2);

    sub_kernel<<<N_GRAPH, 128, 0, stream>>>(Sbuf, h2, subb);
    final_kernel<<<N_GRAPH, 128, 0, stream>>>(subb, Wf1, bf1, Wf2, bf2, out);

    (void)in_sizes; (void)n_in; (void)out_size; (void)ws_size;
}

// Round 4
// 613.107 us; speedup vs baseline: 1.2046x; 1.2046x over previous
//
#include <hip/hip_runtime.h>
#include <hip/hip_bf16.h>
#include <cstdint>

#define N_NODES 51200
#define N_GRAPH 256
#define NPG     200
#define N_EDGE  409600
#define EPG     1600
#define F_IN    768
#define HID     128
#define HEADS   4
#define HC      512   // HEADS*HID

typedef __attribute__((ext_vector_type(8))) short short8;
typedef __attribute__((ext_vector_type(4))) float floatx4;

// ---------------- workspace layout (bytes) ----------------
constexpr size_t OFF_H1B    = 0;                                       // bf16 [N,512] (x@W1, then gat1 out in-place)
constexpr size_t OFF_H2B    = OFF_H1B + (size_t)N_NODES * HC * 2;      // bf16 [N,128] (h1@W2)
constexpr size_t OFF_H2F    = OFF_H2B + (size_t)N_NODES * HID * 2;     // fp32 [N,128] (gat2 out)
constexpr size_t OFF_WT1    = OFF_H2F + (size_t)N_NODES * HID * 4;     // bf16 [512][768]
constexpr size_t OFF_WT2    = OFF_WT1 + (size_t)HC * F_IN * 2;         // bf16 [128][512]
constexpr size_t OFF_S      = OFF_WT2 + (size_t)HID * HC * 2;          // fp32 [N,2]
constexpr size_t OFF_AGG    = OFF_S + (size_t)N_NODES * 2 * 4;
constexpr size_t OFF_SUB    = OFF_AGG + (size_t)N_GRAPH * 4 * 4;

__device__ __forceinline__ float leaky(float x) { return x >= 0.0f ? x : 0.2f * x; }

__device__ __forceinline__ unsigned short f2bf(float f) {
    unsigned int u = __float_as_uint(f);
    u += 0x7fffu + ((u >> 16) & 1u);            // RNE
    return (unsigned short)(u >> 16);
}
__device__ __forceinline__ float bflo(int p) { return __uint_as_float((unsigned)p << 16); }
__device__ __forceinline__ float bfhi(int p) { return __uint_as_float((unsigned)p & 0xffff0000u); }

__device__ __forceinline__ void gl_lds16(const void* g, void* l) {
    __builtin_amdgcn_global_load_lds(
        (__attribute__((address_space(1))) void*)(g),
        (__attribute__((address_space(3))) void*)(l),
        16, 0, 0);
}

// ---------------- W [K][N] fp32 -> Wt [N][K] bf16 ----------------
__global__ __launch_bounds__(256)
void transpose_cvt_kernel(const float* __restrict__ W, short* __restrict__ Wt,
                          int K, int Nn)
{
    int idx = blockIdx.x * 256 + threadIdx.x;
    if (idx >= K * Nn) return;
    int k = idx / Nn, n = idx % Nn;             // coalesced read
    Wt[(size_t)n * K + k] = (short)f2bf(W[idx]);
}

// ---------------- MFMA bf16 GEMM: C[M,Nn] = A[M,K] @ Bt[Nn,K]^T, C bf16 ----------------
template <bool A_BF16>
__global__ __launch_bounds__(256)
void gemm_mfma_kernel(const void* __restrict__ Av, const short* __restrict__ Bt,
                      unsigned short* __restrict__ C, int M, int Nn, int K)
{
    __shared__ __align__(16) short Ablob[4096];   // 8 KB
    __shared__ __align__(16) short Bblob[4096];   // 8 KB
    const int tid = threadIdx.x;
    const int w = tid >> 6, l = tid & 63;
    const int m0 = blockIdx.x * 128, n0 = blockIdx.y * 128;
    const int wr = w >> 1, wc = w & 1;

    floatx4 acc[4][4];
#pragma unroll
    for (int i = 0; i < 4; ++i)
#pragma unroll
        for (int j = 0; j < 4; ++j) acc[i][j] = (floatx4)0.0f;

    const short* bgp = Bt + (size_t)(n0 + (w * 2) * 16 + (l & 15)) * K + ((l >> 4) * 8);

    const float* Af = (const float*)Av;
    const short* Ab = (const short*)Av;
    const int r = tid >> 1, hh = tid & 1;                   // fp32 path
    const float* arow = Af + (size_t)(m0 + r) * K + hh * 16;
    const short* agp = Ab + (size_t)(m0 + (w * 2) * 16 + (l & 15)) * K + ((l >> 4) * 8);

    float4 pf0, pf1, pf2, pf3;
    if constexpr (!A_BF16) {
        pf0 = *(const float4*)(arow + 0);
        pf1 = *(const float4*)(arow + 4);
        pf2 = *(const float4*)(arow + 8);
        pf3 = *(const float4*)(arow + 12);
    }

    for (int k0 = 0; k0 < K; k0 += 32) {
        __syncthreads();
        if constexpr (A_BF16) {
            gl_lds16(agp + k0,          &Ablob[(w * 2) * 512]);
            gl_lds16(agp + 16 * K + k0, &Ablob[(w * 2 + 1) * 512]);
        } else {
            unsigned short us[16];
            us[0]=f2bf(pf0.x); us[1]=f2bf(pf0.y); us[2]=f2bf(pf0.z); us[3]=f2bf(pf0.w);
            us[4]=f2bf(pf1.x); us[5]=f2bf(pf1.y); us[6]=f2bf(pf1.z); us[7]=f2bf(pf1.w);
            us[8]=f2bf(pf2.x); us[9]=f2bf(pf2.y); us[10]=f2bf(pf2.z); us[11]=f2bf(pf2.w);
            us[12]=f2bf(pf3.x); us[13]=f2bf(pf3.y); us[14]=f2bf(pf3.z); us[15]=f2bf(pf3.w);
            const int o = (r >> 4) * 512 + (2 * hh) * 128 + (r & 15) * 8;
            short8 v0, v1;
#pragma unroll
            for (int j = 0; j < 8; ++j) { v0[j] = (short)us[j]; v1[j] = (short)us[8 + j]; }
            *(short8*)&Ablob[o]       = v0;
            *(short8*)&Ablob[o + 128] = v1;
        }
        gl_lds16(bgp + k0,          &Bblob[(w * 2) * 512]);
        gl_lds16(bgp + 16 * K + k0, &Bblob[(w * 2 + 1) * 512]);
        __syncthreads();

        if constexpr (!A_BF16) {
            if (k0 + 32 < K) {
                pf0 = *(const float4*)(arow + k0 + 32);
                pf1 = *(const float4*)(arow + k0 + 36);
                pf2 = *(const float4*)(arow + k0 + 40);
                pf3 = *(const float4*)(arow + k0 + 44);
            }
        }

        short8 af[4], bfr[4];
#pragma unroll
        for (int mi = 0; mi < 4; ++mi)
            af[mi] = *(const short8*)&Ablob[(wr * 4 + mi) * 512 + l * 8];
#pragma unroll
        for (int ni = 0; ni < 4; ++ni)
            bfr[ni] = *(const short8*)&Bblob[(wc * 4 + ni) * 512 + l * 8];
#pragma unroll
        for (int mi = 0; mi < 4; ++mi)
#pragma unroll
            for (int ni = 0; ni < 4; ++ni)
                acc[mi][ni] = __builtin_amdgcn_mfma_f32_16x16x32_bf16(
                    af[mi], bfr[ni], acc[mi][ni], 0, 0, 0);
    }

    const int lr = (l >> 4) * 4, lc = l & 15;   // C/D: col=lane&15, row=(lane>>4)*4+reg
#pragma unroll
    for (int mi = 0; mi < 4; ++mi)
#pragma unroll
        for (int ni = 0; ni < 4; ++ni) {
            const size_t base = (size_t)(m0 + wr * 64 + mi * 16 + lr) * Nn
                              + (n0 + wc * 64 + ni * 16 + lc);
#pragma unroll
            for (int rr = 0; rr < 4; ++rr)
                C[base + (size_t)rr * Nn] = f2bf(acc[mi][ni][rr]);
        }
}

// ---------------- GAT layer 1: fully fused, graph-resident, no cross-lane serialization ----
// block = (graph g, head h). In-block: stage feats, attention dots, CSR build,
// edge-parallel softmax weights in LDS, wave-per-node aggregation. In-place output
// (block writes only the (g,h) slice it staged).
__global__ __launch_bounds__(256)
void gat1_kernel(const unsigned short* __restrict__ H, const int* __restrict__ src0,
                 const int* __restrict__ dst0, const float* __restrict__ a_s,
                 const float* __restrict__ a_d, const float* __restrict__ b1,
                 unsigned short* __restrict__ out)
{
    const int g = blockIdx.x, h = blockIdx.y;
    __shared__ int   s_feat[NPG * 64];     // 51.2 KB packed bf16 pairs
    __shared__ float s_as[NPG], s_ad[NPG], s_m[NPG], s_inv[NPG];
    __shared__ int   s_row[NPG + 1];
    __shared__ int   s_cnt[NPG], s_fill[NPG];
    __shared__ int   s_scan[256];
    __shared__ float s_w[EPG];             // 6.4 KB
    __shared__ short s_esrc[EPG], s_edst[EPG], s_srcl[EPG], s_dstl[EPG];  // 12.8 KB
    const int tid = threadIdx.x, w = tid >> 6, l = tid & 63;
    const int gbase = g * NPG;

    // phase 1: stage feats + raw edges + zero counts
    for (int flat = tid; flat < NPG * 16; flat += 256) {
        int row = flat >> 4, q = flat & 15;
        uint4 v = *(const uint4*)(H + (size_t)(gbase + row) * HC + h * HID + q * 8);
        *(uint4*)&s_feat[row * 64 + q * 4] = v;
    }
    for (int j = tid; j < EPG; j += 256) {
        s_esrc[j] = (short)(src0[g * EPG + j] - gbase);
        s_edst[j] = (short)(dst0[g * EPG + j] - gbase);
    }
    if (tid < NPG) s_cnt[tid] = 0;
    __syncthreads();

    // phase 2: degree histogram (LDS atomics) + attention dots (wave per node)
    for (int j = tid; j < EPG; j += 256)
        atomicAdd(&s_cnt[(int)s_edst[j]], 1);
    const float2 av = ((const float2*)(a_s + h * HID))[l];
    const float2 dv = ((const float2*)(a_d + h * HID))[l];
    for (int nl = w; nl < NPG; nl += 4) {
        int pk = s_feat[nl * 64 + l];
        float f0 = bflo(pk), f1 = bfhi(pk);
        float ss = f0 * av.x + f1 * av.y;
        float sd = f0 * dv.x + f1 * dv.y;
#pragma unroll
        for (int off = 1; off < 64; off <<= 1) {
            ss += __shfl_xor(ss, off);
            sd += __shfl_xor(sd, off);
        }
        if (l == 0) { s_as[nl] = ss; s_ad[nl] = sd; }
    }
    __syncthreads();

    // phase 3: exclusive scan of counts -> s_row; init fill cursors
    {
        int v = (tid < NPG) ? s_cnt[tid] : 0;
        s_scan[tid] = v;
        __syncthreads();
        for (int off = 1; off < 256; off <<= 1) {
            int u = (tid >= off) ? s_scan[tid - off] : 0;
            __syncthreads();
            s_scan[tid] += u;
            __syncthreads();
        }
        if (tid < NPG) s_row[tid + 1] = s_scan[tid];
        if (tid == 0) s_row[0] = 0;
        __syncthreads();
        if (tid < NPG) s_fill[tid] = s_row[tid];
    }
    __syncthreads();

    // phase 4: CSR fill
    for (int j = tid; j < EPG; j += 256) {
        int dg = (int)s_edst[j];
        int p = atomicAdd(&s_fill[dg], 1);
        s_srcl[p] = s_esrc[j];
        s_dstl[p] = (short)dg;
    }
    __syncthreads();

    // phase 5: logits edge-parallel
    for (int j = tid; j < EPG; j += 256)
        s_w[j] = leaky(s_as[(int)s_srcl[j]] + s_ad[(int)s_dstl[j]]);
    __syncthreads();

    // phase 6: per-node max (node-parallel, deg ~8)
    if (tid < NPG) {
        float m = leaky(s_as[tid] + s_ad[tid]);
        int r0 = s_row[tid], r1 = s_row[tid + 1];
        for (int j = r0; j < r1; ++j) m = fmaxf(m, s_w[j]);
        s_m[tid] = m;
    }
    __syncthreads();

    // phase 7: exp edge-parallel
    for (int j = tid; j < EPG; j += 256)
        s_w[j] = __expf(s_w[j] - s_m[(int)s_dstl[j]]);
    __syncthreads();

    // phase 8: per-node sum -> inv
    if (tid < NPG) {
        float rs = __expf(leaky(s_as[tid] + s_ad[tid]) - s_m[tid]);
        int r0 = s_row[tid], r1 = s_row[tid + 1];
        for (int j = r0; j < r1; ++j) rs += s_w[j];
        s_inv[tid] = 1.0f / (rs + 1e-16f);
    }
    __syncthreads();

    // phase 9: aggregation, wave per node, dual accumulators
    const float2 bv = ((const float2*)(b1 + h * HID))[l];
    for (int nl = w; nl < NPG; nl += 4) {
        const int r0 = s_row[nl], r1 = s_row[nl + 1];
        const float wself = __expf(leaky(s_as[nl] + s_ad[nl]) - s_m[nl]);
        int spk = s_feat[nl * 64 + l];
        float a0 = wself * bflo(spk), a1 = wself * bfhi(spk);
        float c0 = 0.0f, c1 = 0.0f;
        int j = r0;
        for (; j + 1 < r1; j += 2) {
            float w0 = s_w[j], w1 = s_w[j + 1];
            int p0 = s_feat[(int)s_srcl[j] * 64 + l];
            int p1 = s_feat[(int)s_srcl[j + 1] * 64 + l];
            a0 += w0 * bflo(p0); a1 += w0 * bfhi(p0);
            c0 += w1 * bflo(p1); c1 += w1 * bfhi(p1);
        }
        if (j < r1) {
            float w0 = s_w[j];
            int p0 = s_feat[(int)s_srcl[j] * 64 + l];
            a0 += w0 * bflo(p0); a1 += w0 * bfhi(p0);
        }
        const float inv = s_inv[nl];
        float o0 = (a0 + c0) * inv + bv.x;
        float o1 = (a1 + c1) * inv + bv.y;
        unsigned int st = (unsigned int)f2bf(fmaxf(o0, 0.0f))
                        | ((unsigned int)f2bf(fmaxf(o1, 0.0f)) << 16);
        *(unsigned int*)&out[(size_t)(gbase + nl) * HC + h * HID + 2 * l] = st;
    }
}

// ---------------- GAT layer 2 + cluster softmax: same structure, 1 head ----------------
__global__ __launch_bounds__(256)
void gat2_kernel(const unsigned short* __restrict__ H, const int* __restrict__ src0,
                 const int* __restrict__ dst0, const float* __restrict__ a_s,
                 const float* __restrict__ a_d, const float* __restrict__ b2,
                 const float* __restrict__ Wc, const float* __restrict__ bc,
                 float* __restrict__ h2, float* __restrict__ S)
{
    const int g = blockIdx.x;
    __shared__ int   s_feat[NPG * 64];
    __shared__ float s_as[NPG], s_ad[NPG], s_m[NPG], s_inv[NPG];
    __shared__ int   s_row[NPG + 1];
    __shared__ int   s_cnt[NPG], s_fill[NPG];
    __shared__ int   s_scan[256];
    __shared__ float s_w[EPG];
    __shared__ short s_esrc[EPG], s_edst[EPG], s_srcl[EPG], s_dstl[EPG];
    const int tid = threadIdx.x, w = tid >> 6, l = tid & 63;
    const int gbase = g * NPG;

    for (int flat = tid; flat < NPG * 16; flat += 256) {
        int row = flat >> 4, q = flat & 15;
        uint4 v = *(const uint4*)(H + (size_t)(gbase + row) * HID + q * 8);
        *(uint4*)&s_feat[row * 64 + q * 4] = v;
    }
    for (int j = tid; j < EPG; j += 256) {
        s_esrc[j] = (short)(src0[g * EPG + j] - gbase);
        s_edst[j] = (short)(dst0[g * EPG + j] - gbase);
    }
    if (tid < NPG) s_cnt[tid] = 0;
    __syncthreads();

    for (int j = tid; j < EPG; j += 256)
        atomicAdd(&s_cnt[(int)s_edst[j]], 1);
    const float2 av = ((const float2*)a_s)[l];
    const float2 dv = ((const float2*)a_d)[l];
    for (int nl = w; nl < NPG; nl += 4) {
        int pk = s_feat[nl * 64 + l];
        float f0 = bflo(pk), f1 = bfhi(pk);
        float ss = f0 * av.x + f1 * av.y;
        float sd = f0 * dv.x + f1 * dv.y;
#pragma unroll
        for (int off = 1; off < 64; off <<= 1) {
            ss += __shfl_xor(ss, off);
            sd += __shfl_xor(sd, off);
        }
        if (l == 0) { s_as[nl] = ss; s_ad[nl] = sd; }
    }
    __syncthreads();

    {
        int v = (tid < NPG) ? s_cnt[tid] : 0;
        s_scan[tid] = v;
        __syncthreads();
        for (int off = 1; off < 256; off <<= 1) {
            int u = (tid >= off) ? s_scan[tid - off] : 0;
            __syncthreads();
            s_scan[tid] += u;
            __syncthreads();
        }
        if (tid < NPG) s_row[tid + 1] = s_scan[tid];
        if (tid == 0) s_row[0] = 0;
        __syncthreads();
        if (tid < NPG) s_fill[tid] = s_row[tid];
    }
    __syncthreads();

    for (int j = tid; j < EPG; j += 256) {
        int dg = (int)s_edst[j];
        int p = atomicAdd(&s_fill[dg], 1);
        s_srcl[p] = s_esrc[j];
        s_dstl[p] = (short)dg;
    }
    __syncthreads();

    for (int j = tid; j < EPG; j += 256)
        s_w[j] = leaky(s_as[(int)s_srcl[j]] + s_ad[(int)s_dstl[j]]);
    __syncthreads();

    if (tid < NPG) {
        float m = leaky(s_as[tid] + s_ad[tid]);
        int r0 = s_row[tid], r1 = s_row[tid + 1];
        for (int j = r0; j < r1; ++j) m = fmaxf(m, s_w[j]);
        s_m[tid] = m;
    }
    __syncthreads();

    for (int j = tid; j < EPG; j += 256)
        s_w[j] = __expf(s_w[j] - s_m[(int)s_dstl[j]]);
    __syncthreads();

    if (tid < NPG) {
        float rs = __expf(leaky(s_as[tid] + s_ad[tid]) - s_m[tid]);
        int r0 = s_row[tid], r1 = s_row[tid + 1];
        for (int j = r0; j < r1; ++j) rs += s_w[j];
        s_inv[tid] = 1.0f / (rs + 1e-16f);
    }
    __syncthreads();

    const float2 bv = ((const float2*)b2)[l];
    const float4 wcv = ((const float4*)Wc)[l];   // Wc[2l][0..1], Wc[2l+1][0..1]
    const float bc0 = bc[0], bc1 = bc[1];
    for (int nl = w; nl < NPG; nl += 4) {
        const int r0 = s_row[nl], r1 = s_row[nl + 1];
        const float wself = __expf(leaky(s_as[nl] + s_ad[nl]) - s_m[nl]);
        int spk = s_feat[nl * 64 + l];
        float a0 = wself * bflo(spk), a1 = wself * bfhi(spk);
        float c0 = 0.0f, c1 = 0.0f;
        int j = r0;
        for (; j + 1 < r1; j += 2) {
            float w0 = s_w[j], w1 = s_w[j + 1];
            int p0 = s_feat[(int)s_srcl[j] * 64 + l];
            int p1 = s_feat[(int)s_srcl[j + 1] * 64 + l];
            a0 += w0 * bflo(p0); a1 += w0 * bfhi(p0);
            c0 += w1 * bflo(p1); c1 += w1 * bfhi(p1);
        }
        if (j < r1) {
            float w0 = s_w[j];
            int p0 = s_feat[(int)s_srcl[j] * 64 + l];
            a0 += w0 * bflo(p0); a1 += w0 * bfhi(p0);
        }
        const float inv = s_inv[nl];
        float o0 = fmaxf((a0 + c0) * inv + bv.x, 0.0f);
        float o1 = fmaxf((a1 + c1) * inv + bv.y, 0.0f);
        *(float2*)&h2[(size_t)(gbase + nl) * HID + 2 * l] = make_float2(o0, o1);
        float z0 = o0 * wcv.x + o1 * wcv.z;
        float z1 = o0 * wcv.y + o1 * wcv.w;
#pragma unroll
        for (int off = 1; off < 64; off <<= 1) {
            z0 += __shfl_xor(z0, off);
            z1 += __shfl_xor(z1, off);
        }
        if (l == 0) {
            z0 += bc0; z1 += bc1;
            float mm = fmaxf(z0, z1);
            float e0 = __expf(z0 - mm), e1 = __expf(z1 - mm);
            float is = 1.0f / (e0 + e1);
            *(float2*)&S[(size_t)(gbase + nl) * 2] = make_float2(e0 * is, e1 * is);
        }
    }
}

// ---------------- per-graph S^T A S (2x2) ----------------
__global__ __launch_bounds__(256)
void agg_kernel(const int* __restrict__ src0, const int* __restrict__ dst0,
                const float* __restrict__ S, float* __restrict__ agg)
{
    const int g = blockIdx.x, tid = threadIdx.x;
    float a00 = 0, a01 = 0, a10 = 0, a11 = 0;
    for (int e = g*EPG + tid; e < (g + 1)*EPG; e += 256) {
        int s = src0[e], d = dst0[e];
        float s0 = S[s*2], s1 = S[s*2 + 1];
        float d0 = S[d*2], d1 = S[d*2 + 1];
        a00 += s0*d0; a01 += s0*d1; a10 += s1*d0; a11 += s1*d1;
    }
    for (int off = 32; off > 0; off >>= 1) {
        a00 += __shfl_down(a00, off); a01 += __shfl_down(a01, off);
        a10 += __shfl_down(a10, off); a11 += __shfl_down(a11, off);
    }
    __shared__ float sred[4][4];
    if ((tid & 63) == 0) {
        int w = tid >> 6;
        sred[w][0] = a00; sred[w][1] = a01; sred[w][2] = a10; sred[w][3] = a11;
    }
    __syncthreads();
    if (tid == 0) {
        agg[g*4 + 0] = sred[0][0] + sred[1][0] + sred[2][0] + sred[3][0];
        agg[g*4 + 1] = sred[0][1] + sred[1][1] + sred[2][1] + sred[3][1];
        agg[g*4 + 2] = sred[0][2] + sred[1][2] + sred[2][2] + sred[3][2];
        agg[g*4 + 3] = sred[0][3] + sred[1][3] + sred[2][3] + sred[3][3];
    }
}

__global__ __launch_bounds__(256)
void loss_kernel(const float* __restrict__ agg, float* __restrict__ out_loss)
{
    int tid = threadIdx.x;   // == graph id, G == 256
    float a00 = agg[tid*4 + 0], a01 = agg[tid*4 + 1];
    float a10 = agg[tid*4 + 2], a11 = agg[tid*4 + 3];
    float rn0 = fmaxf(fabsf(a00) + fabsf(a01), 1e-5f);
    float rn1 = fmaxf(fabsf(a10) + fabsf(a11), 1e-5f);
    float d0 = a00 / rn0 - 1.0f, d1 = a11 / rn1 - 1.0f;
    float contrib = 0.5f * (d0*d0 + d1*d1);
    for (int off = 32; off > 0; off >>= 1) contrib += __shfl_down(contrib, off);
    __shared__ float sred[4];
    if ((tid & 63) == 0) sred[tid >> 6] = contrib;
    __syncthreads();
    if (tid == 0)
        out_loss[0] = (sred[0] + sred[1] + sred[2] + sred[3]) * (1.0f / N_GRAPH);
}

// ---------------- per-graph pooled embedding ----------------
__global__ __launch_bounds__(128)
void sub_kernel(const float* __restrict__ S, const float* __restrict__ h2,
                float* __restrict__ sub)
{
    const int g = blockIdx.x, c = threadIdx.x;
    const float* Sg = S + (size_t)g * NPG * 2;
    const float* hg = h2 + (size_t)g * NPG * HID;
    float acc = 0.0f;
    for (int i = 0; i < NPG; ++i)
        acc += Sg[i*2] * hg[(size_t)i*HID + c];
    sub[g*HID + c] = acc;
}

// ---------------- final MLP head ----------------
__global__ __launch_bounds__(128)
void final_kernel(const float* __restrict__ sub, const float* __restrict__ Wf1,
                  const float* __restrict__ bf1, const float* __restrict__ Wf2,
                  const float* __restrict__ bf2, float* __restrict__ out)
{
    __shared__ float s_sub[128];
    __shared__ float s_fc[128];
    const int g = blockIdx.x, t = threadIdx.x;
    s_sub[t] = sub[g*HID + t];
    __syncthreads();
    float acc = bf1[t];
    for (int c = 0; c < 128; ++c)
        acc += s_sub[c] * Wf1[c*128 + t];
    s_fc[t] = fmaxf(acc, 0.0f);
    __syncthreads();
    if (t < 2) {
        float z = bf2[t];
        for (int j = 0; j < 128; ++j) z += s_fc[j] * Wf2[j*2 + t];
        out[g*2 + t] = z;
    }
}

extern "C" void kernel_launch(void* const* d_in, const int* in_sizes, int n_in,
                              void* d_out, int out_size, void* d_ws, size_t ws_size,
                              hipStream_t stream)
{
    const float* x   = (const float*)d_in[0];
    const int*   ei  = (const int*)d_in[1];
    const float* W1  = (const float*)d_in[3];
    const float* as1 = (const float*)d_in[4];
    const float* ad1 = (const float*)d_in[5];
    const float* b1  = (const float*)d_in[6];
    const float* W2  = (const float*)d_in[7];
    const float* as2 = (const float*)d_in[8];
    const float* ad2 = (const float*)d_in[9];
    const float* b2  = (const float*)d_in[10];
    const float* Wc  = (const float*)d_in[11];
    const float* bc  = (const float*)d_in[12];
    const float* Wf1 = (const float*)d_in[13];
    const float* bf1 = (const float*)d_in[14];
    const float* Wf2 = (const float*)d_in[15];
    const float* bf2 = (const float*)d_in[16];
    const int* src0 = ei;
    const int* dst0 = ei + N_EDGE;

    char* ws = (char*)d_ws;
    unsigned short* H1b = (unsigned short*)(ws + OFF_H1B);
    unsigned short* H2b = (unsigned short*)(ws + OFF_H2B);
    float* h2    = (float*)(ws + OFF_H2F);
    short* Wt1   = (short*)(ws + OFF_WT1);
    short* Wt2   = (short*)(ws + OFF_WT2);
    float* Sbuf  = (float*)(ws + OFF_S);
    float* aggb  = (float*)(ws + OFF_AGG);
    float* subb  = (float*)(ws + OFF_SUB);
    float* out   = (float*)d_out;

    transpose_cvt_kernel<<<(F_IN*HC + 255)/256, 256, 0, stream>>>(W1, Wt1, F_IN, HC);
    transpose_cvt_kernel<<<(HC*HID + 255)/256, 256, 0, stream>>>(W2, Wt2, HC, HID);

    // GEMM1: H1b = bf16(x @ W1)
    gemm_mfma_kernel<false><<<dim3(N_NODES/128, HC/128), 256, 0, stream>>>(
        x, Wt1, H1b, N_NODES, HC, F_IN);

    // GAT1 (fused dots + in-block CSR + softmax + aggregate), in-place on H1b
    gat1_kernel<<<dim3(N_GRAPH, HEADS), 256, 0, stream>>>(
        H1b, src0, dst0, as1, ad1, b1, H1b);

    // GEMM2: H2b = bf16(h1 @ W2)
    gemm_mfma_kernel<true><<<dim3(N_NODES/128, HID/128), 256, 0, stream>>>(
        H1b, Wt2, H2b, N_NODES, HID, HC);

    // GAT2 + cluster softmax S
    gat2_kernel<<<N_GRAPH, 256, 0, stream>>>(
        H2b, src0, dst0, as2, ad2, b2, Wc, bc, h2, Sbuf);

    agg_kernel<<<N_GRAPH, 256, 0, stream>>>(src0, dst0, Sbuf, aggb);
    loss_kernel<<<1, 256, 0, stream>>>(aggb, out + N_GRAPH*2);

    sub_kernel<<<N_GRAPH, 128, 0, stream>>>(Sbuf, h2, subb);
    final_kernel<<<N_GRAPH, 128, 0, stream>>>(subb, Wf1, bf1, Wf2, bf2, out);

    (void)in_sizes; (void)n_in; (void)out_size; (void)ws_size;
}

// Round 5
// 520.071 us; speedup vs baseline: 1.4201x; 1.1789x over previous
//
#include <hip/hip_runtime.h>
#include <hip/hip_bf16.h>
#include <cstdint>

#define N_NODES 51200
#define N_GRAPH 256
#define NPG     200
#define N_EDGE  409600
#define EPG     1600
#define F_IN    768
#define HID     128
#define HEADS   4
#define HC      512   // HEADS*HID

typedef __attribute__((ext_vector_type(8))) short short8;
typedef __attribute__((ext_vector_type(4))) float floatx4;

// ---------------- workspace layout (bytes) ----------------
constexpr size_t OFF_H1B    = 0;                                       // bf16 [N,512] (x@W1, then gat1 out in-place)
constexpr size_t OFF_H2B    = OFF_H1B + (size_t)N_NODES * HC * 2;      // bf16 [N,128] (h1@W2)
constexpr size_t OFF_H2F    = OFF_H2B + (size_t)N_NODES * HID * 2;     // fp32 [N,128] (gat2 out)
constexpr size_t OFF_WT1    = OFF_H2F + (size_t)N_NODES * HID * 4;     // bf16 [512][768]
constexpr size_t OFF_WT2    = OFF_WT1 + (size_t)HC * F_IN * 2;         // bf16 [128][512]
constexpr size_t OFF_S      = OFF_WT2 + (size_t)HID * HC * 2;          // fp32 [N,2]
constexpr size_t OFF_AGG    = OFF_S + (size_t)N_NODES * 2 * 4;
constexpr size_t OFF_SUB    = OFF_AGG + (size_t)N_GRAPH * 4 * 4;

__device__ __forceinline__ float leaky(float x) { return x >= 0.0f ? x : 0.2f * x; }

__device__ __forceinline__ unsigned short f2bf(float f) {
    unsigned int u = __float_as_uint(f);
    u += 0x7fffu + ((u >> 16) & 1u);            // RNE
    return (unsigned short)(u >> 16);
}
__device__ __forceinline__ float bflo(int p) { return __uint_as_float((unsigned)p << 16); }
__device__ __forceinline__ float bfhi(int p) { return __uint_as_float((unsigned)p & 0xffff0000u); }

__device__ __forceinline__ void gl_lds16(const void* g, void* l) {
    __builtin_amdgcn_global_load_lds(
        (__attribute__((address_space(1))) void*)(g),
        (__attribute__((address_space(3))) void*)(l),
        16, 0, 0);
}

// ---------------- W [K][N] fp32 -> Wt [N][K] bf16 ----------------
__global__ __launch_bounds__(256)
void transpose_cvt_kernel(const float* __restrict__ W, short* __restrict__ Wt,
                          int K, int Nn)
{
    int idx = blockIdx.x * 256 + threadIdx.x;
    if (idx >= K * Nn) return;
    int k = idx / Nn, n = idx % Nn;             // coalesced read
    Wt[(size_t)n * K + k] = (short)f2bf(W[idx]);
}

// ---------------- MFMA bf16 GEMM: C[M,Nn] = A[M,K] @ Bt[Nn,K]^T, C bf16 ----------------
template <bool A_BF16>
__global__ __launch_bounds__(256)
void gemm_mfma_kernel(const void* __restrict__ Av, const short* __restrict__ Bt,
                      unsigned short* __restrict__ C, int M, int Nn, int K)
{
    __shared__ __align__(16) short Ablob[4096];   // 8 KB
    __shared__ __align__(16) short Bblob[4096];   // 8 KB
    const int tid = threadIdx.x;
    const int w = tid >> 6, l = tid & 63;
    const int m0 = blockIdx.x * 128, n0 = blockIdx.y * 128;
    const int wr = w >> 1, wc = w & 1;

    floatx4 acc[4][4];
#pragma unroll
    for (int i = 0; i < 4; ++i)
#pragma unroll
        for (int j = 0; j < 4; ++j) acc[i][j] = (floatx4)0.0f;

    const short* bgp = Bt + (size_t)(n0 + (w * 2) * 16 + (l & 15)) * K + ((l >> 4) * 8);

    const float* Af = (const float*)Av;
    const short* Ab = (const short*)Av;
    const int r = tid >> 1, hh = tid & 1;                   // fp32 path
    const float* arow = Af + (size_t)(m0 + r) * K + hh * 16;
    const short* agp = Ab + (size_t)(m0 + (w * 2) * 16 + (l & 15)) * K + ((l >> 4) * 8);

    float4 pf0, pf1, pf2, pf3;
    if constexpr (!A_BF16) {
        pf0 = *(const float4*)(arow + 0);
        pf1 = *(const float4*)(arow + 4);
        pf2 = *(const float4*)(arow + 8);
        pf3 = *(const float4*)(arow + 12);
    }

    for (int k0 = 0; k0 < K; k0 += 32) {
        __syncthreads();
        if constexpr (A_BF16) {
            gl_lds16(agp + k0,          &Ablob[(w * 2) * 512]);
            gl_lds16(agp + 16 * K + k0, &Ablob[(w * 2 + 1) * 512]);
        } else {
            unsigned short us[16];
            us[0]=f2bf(pf0.x); us[1]=f2bf(pf0.y); us[2]=f2bf(pf0.z); us[3]=f2bf(pf0.w);
            us[4]=f2bf(pf1.x); us[5]=f2bf(pf1.y); us[6]=f2bf(pf1.z); us[7]=f2bf(pf1.w);
            us[8]=f2bf(pf2.x); us[9]=f2bf(pf2.y); us[10]=f2bf(pf2.z); us[11]=f2bf(pf2.w);
            us[12]=f2bf(pf3.x); us[13]=f2bf(pf3.y); us[14]=f2bf(pf3.z); us[15]=f2bf(pf3.w);
            const int o = (r >> 4) * 512 + (2 * hh) * 128 + (r & 15) * 8;
            short8 v0, v1;
#pragma unroll
            for (int j = 0; j < 8; ++j) { v0[j] = (short)us[j]; v1[j] = (short)us[8 + j]; }
            *(short8*)&Ablob[o]       = v0;
            *(short8*)&Ablob[o + 128] = v1;
        }
        gl_lds16(bgp + k0,          &Bblob[(w * 2) * 512]);
        gl_lds16(bgp + 16 * K + k0, &Bblob[(w * 2 + 1) * 512]);
        __syncthreads();

        if constexpr (!A_BF16) {
            if (k0 + 32 < K) {
                pf0 = *(const float4*)(arow + k0 + 32);
                pf1 = *(const float4*)(arow + k0 + 36);
                pf2 = *(const float4*)(arow + k0 + 40);
                pf3 = *(const float4*)(arow + k0 + 44);
            }
        }

        short8 af[4], bfr[4];
#pragma unroll
        for (int mi = 0; mi < 4; ++mi)
            af[mi] = *(const short8*)&Ablob[(wr * 4 + mi) * 512 + l * 8];
#pragma unroll
        for (int ni = 0; ni < 4; ++ni)
            bfr[ni] = *(const short8*)&Bblob[(wc * 4 + ni) * 512 + l * 8];
#pragma unroll
        for (int mi = 0; mi < 4; ++mi)
#pragma unroll
            for (int ni = 0; ni < 4; ++ni)
                acc[mi][ni] = __builtin_amdgcn_mfma_f32_16x16x32_bf16(
                    af[mi], bfr[ni], acc[mi][ni], 0, 0, 0);
    }

    const int lr = (l >> 4) * 4, lc = l & 15;   // C/D: col=lane&15, row=(lane>>4)*4+reg
#pragma unroll
    for (int mi = 0; mi < 4; ++mi)
#pragma unroll
        for (int ni = 0; ni < 4; ++ni) {
            const size_t base = (size_t)(m0 + wr * 64 + mi * 16 + lr) * Nn
                              + (n0 + wc * 64 + ni * 16 + lc);
#pragma unroll
            for (int rr = 0; rr < 4; ++rr)
                C[base + (size_t)rr * Nn] = f2bf(acc[mi][ni][rr]);
        }
}

// ---------------- GAT layer 1: fused, graph-resident, 8 waves, ILP-batched gather ----
// block = (graph g, head h). Per-edge record s_wc[j] = {weight bits, src|dst<<8}
// in CSR order: one uniform ds_read_b64 per edge in the hot loop, 4-wide batches.
__global__ __launch_bounds__(512)
void gat1_kernel(const unsigned short* __restrict__ H, const int* __restrict__ src0,
                 const int* __restrict__ dst0, const float* __restrict__ a_s,
                 const float* __restrict__ a_d, const float* __restrict__ b1,
                 unsigned short* __restrict__ out)
{
    const int g = blockIdx.x, h = blockIdx.y;
    __shared__ int   s_feat[NPG * 64];            // 51.2 KB packed bf16 pairs
    __shared__ float s_as[NPG], s_ad[NPG], s_m[NPG], s_inv[NPG];   // 3.2 KB
    __shared__ int   s_row[NPG + 1];
    __shared__ int   s_cnt[NPG];
    __shared__ int   s_scan[256];                 // scan buffer, then fill cursors
    __shared__ unsigned short s_eraw[EPG];        // 3.2 KB: src | dst<<8
    __shared__ int2  s_wc[EPG];                   // 12.8 KB: {weight, src|dst<<8}
    const int tid = threadIdx.x, w = tid >> 6, l = tid & 63;
    const int gbase = g * NPG;

    // phase 1: stage feats + packed edges + zero counts
    for (int flat = tid; flat < NPG * 16; flat += 512) {
        int row = flat >> 4, q = flat & 15;
        uint4 v = *(const uint4*)(H + (size_t)(gbase + row) * HC + h * HID + q * 8);
        *(uint4*)&s_feat[row * 64 + q * 4] = v;
    }
    for (int j = tid; j < EPG; j += 512) {
        int s = src0[g * EPG + j] - gbase;
        int d = dst0[g * EPG + j] - gbase;
        s_eraw[j] = (unsigned short)(s | (d << 8));
    }
    if (tid < NPG) s_cnt[tid] = 0;
    __syncthreads();

    // phase 2: degree histogram + attention dots (wave per node)
    for (int j = tid; j < EPG; j += 512)
        atomicAdd(&s_cnt[s_eraw[j] >> 8], 1);
    const float2 av = ((const float2*)(a_s + h * HID))[l];
    const float2 dv = ((const float2*)(a_d + h * HID))[l];
    for (int nl = w; nl < NPG; nl += 8) {
        int pk = s_feat[nl * 64 + l];
        float f0 = bflo(pk), f1 = bfhi(pk);
        float ss = f0 * av.x + f1 * av.y;
        float sd = f0 * dv.x + f1 * dv.y;
#pragma unroll
        for (int off = 1; off < 64; off <<= 1) {
            ss += __shfl_xor(ss, off);
            sd += __shfl_xor(sd, off);
        }
        if (l == 0) { s_as[nl] = ss; s_ad[nl] = sd; }
    }
    __syncthreads();

    // phase 3: exclusive scan -> s_row; fill cursors in s_scan
    {
        int v = (tid < NPG) ? s_cnt[tid] : 0;
        if (tid < 256) s_scan[tid] = v;
        __syncthreads();
        for (int off = 1; off < 256; off <<= 1) {
            int u = (tid >= off && tid < 256) ? s_scan[tid - off] : 0;
            __syncthreads();
            if (tid < 256) s_scan[tid] += u;
            __syncthreads();
        }
        if (tid < NPG) s_row[tid + 1] = s_scan[tid];
        if (tid == 0) s_row[0] = 0;
        __syncthreads();
        if (tid < NPG) s_scan[tid] = s_row[tid];   // fill cursors
    }
    __syncthreads();

    // phase 4: CSR fill (packed indices into s_wc.y)
    for (int j = tid; j < EPG; j += 512) {
        int pk = s_eraw[j];
        int p = atomicAdd(&s_scan[pk >> 8], 1);
        s_wc[p].y = pk;
    }
    __syncthreads();

    // phase 5: logits edge-parallel
    for (int j = tid; j < EPG; j += 512) {
        int pk = s_wc[j].y;
        s_wc[j].x = __float_as_int(leaky(s_as[pk & 255] + s_ad[pk >> 8]));
    }
    __syncthreads();

    // phase 6: per-node max
    if (tid < NPG) {
        float m = leaky(s_as[tid] + s_ad[tid]);
        int r0 = s_row[tid], r1 = s_row[tid + 1];
        for (int j = r0; j < r1; ++j) m = fmaxf(m, __int_as_float(s_wc[j].x));
        s_m[tid] = m;
    }
    __syncthreads();

    // phase 7: exp edge-parallel
    for (int j = tid; j < EPG; j += 512) {
        int2 e = s_wc[j];
        s_wc[j].x = __float_as_int(__expf(__int_as_float(e.x) - s_m[e.y >> 8]));
    }
    __syncthreads();

    // phase 8: per-node sum -> inv
    if (tid < NPG) {
        float rs = __expf(leaky(s_as[tid] + s_ad[tid]) - s_m[tid]);
        int r0 = s_row[tid], r1 = s_row[tid + 1];
        for (int j = r0; j < r1; ++j) rs += __int_as_float(s_wc[j].x);
        s_inv[tid] = 1.0f / (rs + 1e-16f);
    }
    __syncthreads();

    // phase 9: aggregation, wave per node, 4-wide batches, dual acc pairs
    const float2 bv = ((const float2*)(b1 + h * HID))[l];
    for (int nl = w; nl < NPG; nl += 8) {
        const int r0 = s_row[nl], r1 = s_row[nl + 1];
        const float wself = __expf(leaky(s_as[nl] + s_ad[nl]) - s_m[nl]);
        int spk = s_feat[nl * 64 + l];
        float a0 = wself * bflo(spk), a1 = wself * bfhi(spk);
        float c0 = 0.0f, c1 = 0.0f;
        int j = r0;
        for (; j + 4 <= r1; j += 4) {
            int2 e0 = s_wc[j], e1 = s_wc[j + 1], e2 = s_wc[j + 2], e3 = s_wc[j + 3];
            int p0 = s_feat[(e0.y & 255) * 64 + l];
            int p1 = s_feat[(e1.y & 255) * 64 + l];
            int p2 = s_feat[(e2.y & 255) * 64 + l];
            int p3 = s_feat[(e3.y & 255) * 64 + l];
            float w0 = __int_as_float(e0.x), w1 = __int_as_float(e1.x);
            float w2 = __int_as_float(e2.x), w3 = __int_as_float(e3.x);
            a0 += w0 * bflo(p0); a1 += w0 * bfhi(p0);
            c0 += w1 * bflo(p1); c1 += w1 * bfhi(p1);
            a0 += w2 * bflo(p2); a1 += w2 * bfhi(p2);
            c0 += w3 * bflo(p3); c1 += w3 * bfhi(p3);
        }
        for (; j < r1; ++j) {
            int2 e0 = s_wc[j];
            int p0 = s_feat[(e0.y & 255) * 64 + l];
            float w0 = __int_as_float(e0.x);
            a0 += w0 * bflo(p0); a1 += w0 * bfhi(p0);
        }
        const float inv = s_inv[nl];
        float o0 = (a0 + c0) * inv + bv.x;
        float o1 = (a1 + c1) * inv + bv.y;
        unsigned int st = (unsigned int)f2bf(fmaxf(o0, 0.0f))
                        | ((unsigned int)f2bf(fmaxf(o1, 0.0f)) << 16);
        *(unsigned int*)&out[(size_t)(gbase + nl) * HC + h * HID + 2 * l] = st;
    }
}

// ---------------- GAT layer 2 + cluster softmax: same structure, 1 head ----------------
__global__ __launch_bounds__(512)
void gat2_kernel(const unsigned short* __restrict__ H, const int* __restrict__ src0,
                 const int* __restrict__ dst0, const float* __restrict__ a_s,
                 const float* __restrict__ a_d, const float* __restrict__ b2,
                 const float* __restrict__ Wc, const float* __restrict__ bc,
                 float* __restrict__ h2, float* __restrict__ S)
{
    const int g = blockIdx.x;
    __shared__ int   s_feat[NPG * 64];
    __shared__ float s_as[NPG], s_ad[NPG], s_m[NPG], s_inv[NPG];
    __shared__ int   s_row[NPG + 1];
    __shared__ int   s_cnt[NPG];
    __shared__ int   s_scan[256];
    __shared__ unsigned short s_eraw[EPG];
    __shared__ int2  s_wc[EPG];
    const int tid = threadIdx.x, w = tid >> 6, l = tid & 63;
    const int gbase = g * NPG;

    for (int flat = tid; flat < NPG * 16; flat += 512) {
        int row = flat >> 4, q = flat & 15;
        uint4 v = *(const uint4*)(H + (size_t)(gbase + row) * HID + q * 8);
        *(uint4*)&s_feat[row * 64 + q * 4] = v;
    }
    for (int j = tid; j < EPG; j += 512) {
        int s = src0[g * EPG + j] - gbase;
        int d = dst0[g * EPG + j] - gbase;
        s_eraw[j] = (unsigned short)(s | (d << 8));
    }
    if (tid < NPG) s_cnt[tid] = 0;
    __syncthreads();

    for (int j = tid; j < EPG; j += 512)
        atomicAdd(&s_cnt[s_eraw[j] >> 8], 1);
    const float2 av = ((const float2*)a_s)[l];
    const float2 dv = ((const float2*)a_d)[l];
    for (int nl = w; nl < NPG; nl += 8) {
        int pk = s_feat[nl * 64 + l];
        float f0 = bflo(pk), f1 = bfhi(pk);
        float ss = f0 * av.x + f1 * av.y;
        float sd = f0 * dv.x + f1 * dv.y;
#pragma unroll
        for (int off = 1; off < 64; off <<= 1) {
            ss += __shfl_xor(ss, off);
            sd += __shfl_xor(sd, off);
        }
        if (l == 0) { s_as[nl] = ss; s_ad[nl] = sd; }
    }
    __syncthreads();

    {
        int v = (tid < NPG) ? s_cnt[tid] : 0;
        if (tid < 256) s_scan[tid] = v;
        __syncthreads();
        for (int off = 1; off < 256; off <<= 1) {
            int u = (tid >= off && tid < 256) ? s_scan[tid - off] : 0;
            __syncthreads();
            if (tid < 256) s_scan[tid] += u;
            __syncthreads();
        }
        if (tid < NPG) s_row[tid + 1] = s_scan[tid];
        if (tid == 0) s_row[0] = 0;
        __syncthreads();
        if (tid < NPG) s_scan[tid] = s_row[tid];
    }
    __syncthreads();

    for (int j = tid; j < EPG; j += 512) {
        int pk = s_eraw[j];
        int p = atomicAdd(&s_scan[pk >> 8], 1);
        s_wc[p].y = pk;
    }
    __syncthreads();

    for (int j = tid; j < EPG; j += 512) {
        int pk = s_wc[j].y;
        s_wc[j].x = __float_as_int(leaky(s_as[pk & 255] + s_ad[pk >> 8]));
    }
    __syncthreads();

    if (tid < NPG) {
        float m = leaky(s_as[tid] + s_ad[tid]);
        int r0 = s_row[tid], r1 = s_row[tid + 1];
        for (int j = r0; j < r1; ++j) m = fmaxf(m, __int_as_float(s_wc[j].x));
        s_m[tid] = m;
    }
    __syncthreads();

    for (int j = tid; j < EPG; j += 512) {
        int2 e = s_wc[j];
        s_wc[j].x = __float_as_int(__expf(__int_as_float(e.x) - s_m[e.y >> 8]));
    }
    __syncthreads();

    if (tid < NPG) {
        float rs = __expf(leaky(s_as[tid] + s_ad[tid]) - s_m[tid]);
        int r0 = s_row[tid], r1 = s_row[tid + 1];
        for (int j = r0; j < r1; ++j) rs += __int_as_float(s_wc[j].x);
        s_inv[tid] = 1.0f / (rs + 1e-16f);
    }
    __syncthreads();

    const float2 bv = ((const float2*)b2)[l];
    const float4 wcv = ((const float4*)Wc)[l];   // Wc[2l][0..1], Wc[2l+1][0..1]
    const float bc0 = bc[0], bc1 = bc[1];
    for (int nl = w; nl < NPG; nl += 8) {
        const int r0 = s_row[nl], r1 = s_row[nl + 1];
        const float wself = __expf(leaky(s_as[nl] + s_ad[nl]) - s_m[nl]);
        int spk = s_feat[nl * 64 + l];
        float a0 = wself * bflo(spk), a1 = wself * bfhi(spk);
        float c0 = 0.0f, c1 = 0.0f;
        int j = r0;
        for (; j + 4 <= r1; j += 4) {
            int2 e0 = s_wc[j], e1 = s_wc[j + 1], e2 = s_wc[j + 2], e3 = s_wc[j + 3];
            int p0 = s_feat[(e0.y & 255) * 64 + l];
            int p1 = s_feat[(e1.y & 255) * 64 + l];
            int p2 = s_feat[(e2.y & 255) * 64 + l];
            int p3 = s_feat[(e3.y & 255) * 64 + l];
            float w0 = __int_as_float(e0.x), w1 = __int_as_float(e1.x);
            float w2 = __int_as_float(e2.x), w3 = __int_as_float(e3.x);
            a0 += w0 * bflo(p0); a1 += w0 * bfhi(p0);
            c0 += w1 * bflo(p1); c1 += w1 * bfhi(p1);
            a0 += w2 * bflo(p2); a1 += w2 * bfhi(p2);
            c0 += w3 * bflo(p3); c1 += w3 * bfhi(p3);
        }
        for (; j < r1; ++j) {
            int2 e0 = s_wc[j];
            int p0 = s_feat[(e0.y & 255) * 64 + l];
            float w0 = __int_as_float(e0.x);
            a0 += w0 * bflo(p0); a1 += w0 * bfhi(p0);
        }
        const float inv = s_inv[nl];
        float o0 = fmaxf((a0 + c0) * inv + bv.x, 0.0f);
        float o1 = fmaxf((a1 + c1) * inv + bv.y, 0.0f);
        *(float2*)&h2[(size_t)(gbase + nl) * HID + 2 * l] = make_float2(o0, o1);
        float z0 = o0 * wcv.x + o1 * wcv.z;
        float z1 = o0 * wcv.y + o1 * wcv.w;
#pragma unroll
        for (int off = 1; off < 64; off <<= 1) {
            z0 += __shfl_xor(z0, off);
            z1 += __shfl_xor(z1, off);
        }
        if (l == 0) {
            z0 += bc0; z1 += bc1;
            float mm = fmaxf(z0, z1);
            float e0 = __expf(z0 - mm), e1 = __expf(z1 - mm);
            float is = 1.0f / (e0 + e1);
            *(float2*)&S[(size_t)(gbase + nl) * 2] = make_float2(e0 * is, e1 * is);
        }
    }
}

// ---------------- per-graph S^T A S (2x2) ----------------
__global__ __launch_bounds__(256)
void agg_kernel(const int* __restrict__ src0, const int* __restrict__ dst0,
                const float* __restrict__ S, float* __restrict__ agg)
{
    const int g = blockIdx.x, tid = threadIdx.x;
    float a00 = 0, a01 = 0, a10 = 0, a11 = 0;
    for (int e = g*EPG + tid; e < (g + 1)*EPG; e += 256) {
        int s = src0[e], d = dst0[e];
        float s0 = S[s*2], s1 = S[s*2 + 1];
        float d0 = S[d*2], d1 = S[d*2 + 1];
        a00 += s0*d0; a01 += s0*d1; a10 += s1*d0; a11 += s1*d1;
    }
    for (int off = 32; off > 0; off >>= 1) {
        a00 += __shfl_down(a00, off); a01 += __shfl_down(a01, off);
        a10 += __shfl_down(a10, off); a11 += __shfl_down(a11, off);
    }
    __shared__ float sred[4][4];
    if ((tid & 63) == 0) {
        int w = tid >> 6;
        sred[w][0] = a00; sred[w][1] = a01; sred[w][2] = a10; sred[w][3] = a11;
    }
    __syncthreads();
    if (tid == 0) {
        agg[g*4 + 0] = sred[0][0] + sred[1][0] + sred[2][0] + sred[3][0];
        agg[g*4 + 1] = sred[0][1] + sred[1][1] + sred[2][1] + sred[3][1];
        agg[g*4 + 2] = sred[0][2] + sred[1][2] + sred[2][2] + sred[3][2];
        agg[g*4 + 3] = sred[0][3] + sred[1][3] + sred[2][3] + sred[3][3];
    }
}

__global__ __launch_bounds__(256)
void loss_kernel(const float* __restrict__ agg, float* __restrict__ out_loss)
{
    int tid = threadIdx.x;   // == graph id, G == 256
    float a00 = agg[tid*4 + 0], a01 = agg[tid*4 + 1];
    float a10 = agg[tid*4 + 2], a11 = agg[tid*4 + 3];
    float rn0 = fmaxf(fabsf(a00) + fabsf(a01), 1e-5f);
    float rn1 = fmaxf(fabsf(a10) + fabsf(a11), 1e-5f);
    float d0 = a00 / rn0 - 1.0f, d1 = a11 / rn1 - 1.0f;
    float contrib = 0.5f * (d0*d0 + d1*d1);
    for (int off = 32; off > 0; off >>= 1) contrib += __shfl_down(contrib, off);
    __shared__ float sred[4];
    if ((tid & 63) == 0) sred[tid >> 6] = contrib;
    __syncthreads();
    if (tid == 0)
        out_loss[0] = (sred[0] + sred[1] + sred[2] + sred[3]) * (1.0f / N_GRAPH);
}

// ---------------- per-graph pooled embedding ----------------
__global__ __launch_bounds__(128)
void sub_kernel(const float* __restrict__ S, const float* __restrict__ h2,
                float* __restrict__ sub)
{
    const int g = blockIdx.x, c = threadIdx.x;
    const float* Sg = S + (size_t)g * NPG * 2;
    const float* hg = h2 + (size_t)g * NPG * HID;
    float acc = 0.0f;
    for (int i = 0; i < NPG; ++i)
        acc += Sg[i*2] * hg[(size_t)i*HID + c];
    sub[g*HID + c] = acc;
}

// ---------------- final MLP head ----------------
__global__ __launch_bounds__(128)
void final_kernel(const float* __restrict__ sub, const float* __restrict__ Wf1,
                  const float* __restrict__ bf1, const float* __restrict__ Wf2,
                  const float* __restrict__ bf2, float* __restrict__ out)
{
    __shared__ float s_sub[128];
    __shared__ float s_fc[128];
    const int g = blockIdx.x, t = threadIdx.x;
    s_sub[t] = sub[g*HID + t];
    __syncthreads();
    float acc = bf1[t];
    for (int c = 0; c < 128; ++c)
        acc += s_sub[c] * Wf1[c*128 + t];
    s_fc[t] = fmaxf(acc, 0.0f);
    __syncthreads();
    if (t < 2) {
        float z = bf2[t];
        for (int j = 0; j < 128; ++j) z += s_fc[j] * Wf2[j*2 + t];
        out[g*2 + t] = z;
    }
}

extern "C" void kernel_launch(void* const* d_in, const int* in_sizes, int n_in,
                              void* d_out, int out_size, void* d_ws, size_t ws_size,
                              hipStream_t stream)
{
    const float* x   = (const float*)d_in[0];
    const int*   ei  = (const int*)d_in[1];
    const float* W1  = (const float*)d_in[3];
    const float* as1 = (const float*)d_in[4];
    const float* ad1 = (const float*)d_in[5];
    const float* b1  = (const float*)d_in[6];
    const float* W2  = (const float*)d_in[7];
    const float* as2 = (const float*)d_in[8];
    const float* ad2 = (const float*)d_in[9];
    const float* b2  = (const float*)d_in[10];
    const float* Wc  = (const float*)d_in[11];
    const float* bc  = (const float*)d_in[12];
    const float* Wf1 = (const float*)d_in[13];
    const float* bf1 = (const float*)d_in[14];
    const float* Wf2 = (const float*)d_in[15];
    const float* bf2 = (const float*)d_in[16];
    const int* src0 = ei;
    const int* dst0 = ei + N_EDGE;

    char* ws = (char*)d_ws;
    unsigned short* H1b = (unsigned short*)(ws + OFF_H1B);
    unsigned short* H2b = (unsigned short*)(ws + OFF_H2B);
    float* h2    = (float*)(ws + OFF_H2F);
    short* Wt1   = (short*)(ws + OFF_WT1);
    short* Wt2   = (short*)(ws + OFF_WT2);
    float* Sbuf  = (float*)(ws + OFF_S);
    float* aggb  = (float*)(ws + OFF_AGG);
    float* subb  = (float*)(ws + OFF_SUB);
    float* out   = (float*)d_out;

    transpose_cvt_kernel<<<(F_IN*HC + 255)/256, 256, 0, stream>>>(W1, Wt1, F_IN, HC);
    transpose_cvt_kernel<<<(HC*HID + 255)/256, 256, 0, stream>>>(W2, Wt2, HC, HID);

    // GEMM1: H1b = bf16(x @ W1)
    gemm_mfma_kernel<false><<<dim3(N_NODES/128, HC/128), 256, 0, stream>>>(
        x, Wt1, H1b, N_NODES, HC, F_IN);

    // GAT1 (fused dots + in-block CSR + softmax + aggregate), in-place on H1b
    gat1_kernel<<<dim3(N_GRAPH, HEADS), 512, 0, stream>>>(
        H1b, src0, dst0, as1, ad1, b1, H1b);

    // GEMM2: H2b = bf16(h1 @ W2)
    gemm_mfma_kernel<true><<<dim3(N_NODES/128, HID/128), 256, 0, stream>>>(
        H1b, Wt2, H2b, N_NODES, HID, HC);

    // GAT2 + cluster softmax S
    gat2_kernel<<<N_GRAPH, 512, 0, stream>>>(
        H2b, src0, dst0, as2, ad2, b2, Wc, bc, h2, Sbuf);

    agg_kernel<<<N_GRAPH, 256, 0, stream>>>(src0, dst0, Sbuf, aggb);
    loss_kernel<<<1, 256, 0, stream>>>(aggb, out + N_GRAPH*2);

    sub_kernel<<<N_GRAPH, 128, 0, stream>>>(Sbuf, h2, subb);
    final_kernel<<<N_GRAPH, 128, 0, stream>>>(subb, Wf1, bf1, Wf2, bf2, out);

    (void)in_sizes; (void)n_in; (void)out_size; (void)ws_size;
}